// Round 6
// baseline (180.909 us; speedup 1.0000x reference)
//
#include <hip/hip_runtime.h>
#include <math.h>

#define B 16
#define A 3
#define W 128
#define HW 16384          // 128*128
#define NCH 255
#define NCLS 80
#define NCAND 49152       // HW*A
#define K 100
#define NBINS 4096
#define CAP 1024
#define BLKS_PER_IMG 12   // 12 blocks x 1024 thr x 4 cells = 49152 cells/image

__device__ __forceinline__ float sigmoidf_(float v) {
    return 1.0f / (1.0f + expf(-v));
}

__device__ __forceinline__ bool pair_before(float sa, int ia, float sb, int ib) {
    // "a comes before b" in descending-score, ascending-index order
    return (sa > sb) || (sa == sb && ia < ib);
}

// ---- tiny init kernel: zero the per-image completion counters --------------
__global__ __launch_bounds__(64) void k_zero(unsigned int* __restrict__ done) {
    if (threadIdx.x < B) done[threadIdx.x] = 0u;
}

// ---- fused kernel: streaming score/argmax + last-block-per-image tail ------
__global__ __launch_bounds__(1024, 8) void k_fused(const float* __restrict__ x,
                                                   const float* __restrict__ anchors,
                                                   float* __restrict__ scores,
                                                   unsigned char* __restrict__ labels,
                                                   unsigned int* __restrict__ done,
                                                   float* __restrict__ out) {
    // tail LDS (allocated always; ~30 KB -> 2 blocks/CU, thread-capped anyway)
    __shared__ unsigned int lh[NBINS];        // 16 KB
    __shared__ int sh_thr;
    __shared__ unsigned int sh_cnt;
    __shared__ float cs[CAP];
    __shared__ int ci[CAP];
    __shared__ float ts[K];
    __shared__ int tix[K];
    __shared__ float bxs[K][4];
    __shared__ float area[K];
    __shared__ int lab[K];
    __shared__ unsigned int sup[K][4];
    __shared__ unsigned int keepw[4];
    __shared__ int lastf;

    int bid = blockIdx.x;
    int b = bid / BLKS_PER_IMG;
    int seg = bid % BLKS_PER_IMG;
    int tid = threadIdx.x;

    // ---------------- phase 1: score + class argmax for 4 cells ------------
    {
        int off = seg * 4096 + tid * 4;        // flat [a][hw] offset, 4096-aligned seg
        int a = off >> 14;
        int hw = off & (HW - 1);
        const float* base = x + (size_t)(b * NCH + a * 85) * HW + hw;

        float4 o4 = *(const float4*)(base + 4 * HW);
        float4 m4 = *(const float4*)(base + 5 * HW);
        int amx = 0, amy = 0, amz = 0, amw = 0;
        #pragma unroll
        for (int c = 1; c < NCLS; ++c) {
            float4 v = *(const float4*)(base + (size_t)(5 + c) * HW);
            bool gx = v.x > m4.x; amx = gx ? c : amx; m4.x = gx ? v.x : m4.x;
            bool gy = v.y > m4.y; amy = gy ? c : amy; m4.y = gy ? v.y : m4.y;
            bool gz = v.z > m4.z; amz = gz ? c : amz; m4.z = gz ? v.z : m4.z;
            bool gw = v.w > m4.w; amw = gw ? c : amw; m4.w = gw ? v.w : m4.w;
        }
        float ol[4] = {o4.x, o4.y, o4.z, o4.w};
        float ml[4] = {m4.x, m4.y, m4.z, m4.w};
        float outv[4];
        #pragma unroll
        for (int l = 0; l < 4; ++l) {
            float obj = sigmoidf_(ol[l]);
            float cls = sigmoidf_(ml[l]);      // sigmoid monotone: max(sig)=sig(max)
            float sc = obj * cls;
            bool valid = (obj >= 0.5f) && (sc >= 0.05f);
            outv[l] = valid ? sc : -1.0f;
        }
        size_t soff = (size_t)b * NCAND + off;    // [b][a][hw] layout
        *(float4*)(scores + soff) = make_float4(outv[0], outv[1], outv[2], outv[3]);
        *(uchar4*)(labels + soff) = make_uchar4((unsigned char)amx, (unsigned char)amy,
                                                (unsigned char)amz, (unsigned char)amw);
    }

    // ---------------- completion protocol (release -> count -> acquire) ----
    __threadfence();          // release: make this block's stores visible device-wide
    __syncthreads();
    if (tid == 0) {
        unsigned int old = atomicAdd(&done[b], 1u);
        lastf = (old == BLKS_PER_IMG - 1) ? 1 : 0;
    }
    __syncthreads();
    if (!lastf) return;
    __threadfence();          // acquire: see all sibling blocks' stores

    // ---------------- phase 2: per-image tail (1024 threads) ---------------
    const float* sb = scores + (size_t)b * NCAND;

    for (int i = tid; i < NBINS; i += 1024) lh[i] = 0;
    if (tid == 0) { sh_thr = 0; sh_cnt = 0; }
    if (tid < 4) keepw[tid] = 0u;
    for (int i = tid; i < K * 4; i += 1024) ((unsigned int*)sup)[i] = 0u;
    if (tid < K) { ts[tid] = -3.0f; tix[tid] = 0x7FFFFFFF; }
    __syncthreads();

    // pass 1: histogram of valid scores (L2/L3-resident read)
    #pragma unroll
    for (int it = 0; it < 12; ++it) {
        int o = (it * 1024 + tid) * 4;
        float4 v = *(const float4*)(sb + o);
        float sv[4] = {v.x, v.y, v.z, v.w};
        #pragma unroll
        for (int l = 0; l < 4; ++l) {
            float s = sv[l];
            if (s > 0.0f) {
                int bin = (int)(s * (float)NBINS);
                bin = bin > NBINS - 1 ? NBINS - 1 : bin;
                atomicAdd(&lh[bin], 1u);
            }
        }
    }
    __syncthreads();

    // single-wave suffix scan: wave 0 only, no barriers inside
    if (tid < 64) {
        unsigned int c = 0;
        #pragma unroll
        for (int j = 0; j < 64; ++j)
            c += lh[tid * 64 + ((j + tid) & 63)];   // rotated: bank-conflict-free
        unsigned int s = c;
        #pragma unroll
        for (int off = 1; off < 64; off <<= 1) {
            unsigned int v = __shfl_down(s, off);
            if (tid + off < 64) s += v;
        }
        unsigned long long mask = __ballot(s >= K);
        int lstar = -1;
        if (mask) lstar = 63 - __clzll(mask);
        unsigned int snext = 0;
        if (lstar >= 0 && lstar < 63) snext = (unsigned int)__shfl((int)s, lstar + 1);
        if (lstar >= 0 && tid == lstar) {
            unsigned int running = snext;
            int result = lstar * 64;
            for (int bin = lstar * 64 + 63; bin >= lstar * 64; --bin) {
                running += lh[bin];
                if (running >= K) { result = bin; break; }
            }
            sh_thr = result;
        }
        // lstar < 0 (fewer than K valid): sh_thr stays 0 -> take all valid
    }
    __syncthreads();

    // pass 2: compact survivors (bin >= thr) into LDS
    int thr = sh_thr;
    #pragma unroll
    for (int it = 0; it < 12; ++it) {
        int o = (it * 1024 + tid) * 4;
        float4 v = *(const float4*)(sb + o);
        float sv[4] = {v.x, v.y, v.z, v.w};
        #pragma unroll
        for (int l = 0; l < 4; ++l) {
            float s = sv[l];
            if (s > 0.0f && (int)(s * (float)NBINS) >= thr) {
                unsigned int p = atomicAdd(&sh_cnt, 1u);
                if (p < CAP) {
                    int so = o + l;                 // storage offset a*HW+hw
                    int aa = so >> 14;
                    int hh = so & (HW - 1);
                    cs[p] = s;
                    ci[p] = hh * A + aa;            // reference flat index
                }
            }
        }
    }
    __syncthreads();
    int n = (int)sh_cnt; if (n > CAP) n = CAP;

    // one-pass rank select: rank = #pairs strictly before me
    if (tid < n) {
        float s0 = cs[tid]; int i0 = ci[tid];
        int rank = 0;
        for (int j = 0; j < n; ++j)
            rank += pair_before(cs[j], ci[j], s0, i0) ? 1 : 0;
        if (rank < K) { ts[rank] = s0; tix[rank] = i0; }
    }
    __syncthreads();

    // decode boxes + label for valid top-K
    if (tid < K && ts[tid] > 0.0f) {
        int nidx = tix[tid];
        int a = nidx % A;
        int hw = nidx / A;
        int cx = hw % W;
        int cy = hw / W;
        const float* base = x + (size_t)(b * NCH + a * 85) * HW + hw;
        float tx = base[0];
        float ty = base[HW];
        float tw = base[2 * HW];
        float th = base[3 * HW];
        float bcx = (sigmoidf_(tx) + (float)cx) / 128.0f;
        float bcy = (sigmoidf_(ty) + (float)cy) / 128.0f;
        float bw = fminf(fmaxf(expf(tw) * anchors[a * 2 + 0], 0.0f), 2.0f);
        float bh = fminf(fmaxf(expf(th) * anchors[a * 2 + 1], 0.0f), 2.0f);
        float x1 = bcx - 0.5f * bw;
        float y1 = bcy - 0.5f * bh;
        float x2 = x1 + bw;
        float y2 = y1 + bh;
        x1 = fminf(fmaxf(x1, 0.0f), 1.0f);
        y1 = fminf(fmaxf(y1, 0.0f), 1.0f);
        x2 = fminf(fmaxf(x2, 0.0f), 1.0f);
        y2 = fminf(fmaxf(y2, 0.0f), 1.0f);
        bxs[tid][0] = x1; bxs[tid][1] = y1; bxs[tid][2] = x2; bxs[tid][3] = y2;
        area[tid] = fmaxf(x2 - x1, 0.0f) * fmaxf(y2 - y1, 0.0f);
        lab[tid] = (int)labels[(size_t)b * NCAND + a * HW + hw];
        atomicOr(&keepw[tid >> 5], 1u << (tid & 31));
    }
    __syncthreads();

    // IoU suppression bitmasks (j > i, both valid)
    for (int p = tid; p < K * K; p += 1024) {
        int i = p / K, j = p % K;
        if (j > i && ts[i] > 0.0f && ts[j] > 0.0f) {
            float lx = fmaxf(bxs[i][0], bxs[j][0]);
            float ly = fmaxf(bxs[i][1], bxs[j][1]);
            float rx = fminf(bxs[i][2], bxs[j][2]);
            float ry = fminf(bxs[i][3], bxs[j][3]);
            float iw = fmaxf(rx - lx, 0.0f);
            float ih = fmaxf(ry - ly, 0.0f);
            float inter = iw * ih;
            float uni = area[i] + area[j] - inter;
            float iou = inter / fmaxf(uni, 1e-12f);
            if (iou > 0.7f) atomicOr(&sup[i][j >> 5], 1u << (j & 31));
        }
    }
    __syncthreads();

    // greedy scan (register bit-ops, one thread)
    if (tid == 0) {
        unsigned int kw0 = keepw[0], kw1 = keepw[1], kw2 = keepw[2], kw3 = keepw[3];
        for (int i = 0; i < K; ++i) {
            unsigned int kwi = (i < 32) ? kw0 : (i < 64) ? kw1 : (i < 96) ? kw2 : kw3;
            if ((kwi >> (i & 31)) & 1u) {
                kw0 &= ~sup[i][0];
                kw1 &= ~sup[i][1];
                kw2 &= ~sup[i][2];
                kw3 &= ~sup[i][3];
            }
        }
        keepw[0] = kw0; keepw[1] = kw1; keepw[2] = kw2; keepw[3] = kw3;
    }
    __syncthreads();

    // write outputs: boxes | scores | labels | keep (all float32, flat)
    if (tid < K) {
        int kp = (keepw[tid >> 5] >> (tid & 31)) & 1u;
        float sc = ts[tid];
        float* ob = out + (size_t)b * K * 4;
        float* osc = out + (size_t)B * K * 4;
        float* olab = osc + (size_t)B * K;
        float* okp = olab + (size_t)B * K;
        ob[tid * 4 + 0] = kp ? bxs[tid][0] : 0.0f;
        ob[tid * 4 + 1] = kp ? bxs[tid][1] : 0.0f;
        ob[tid * 4 + 2] = kp ? bxs[tid][2] : 0.0f;
        ob[tid * 4 + 3] = kp ? bxs[tid][3] : 0.0f;
        osc[b * K + tid] = kp ? sc : 0.0f;
        olab[b * K + tid] = kp ? (float)lab[tid] : -1.0f;
        okp[b * K + tid] = kp ? 1.0f : 0.0f;
    }
}

extern "C" void kernel_launch(void* const* d_in, const int* in_sizes, int n_in,
                              void* d_out, int out_size, void* d_ws, size_t ws_size,
                              hipStream_t stream) {
    const float* x = (const float*)d_in[0];
    const float* anchors = (const float*)d_in[1];
    float* out = (float*)d_out;

    float* scores = (float*)d_ws;                                         // B*NCAND f32 (3 MB)
    unsigned char* labels = (unsigned char*)(scores + (size_t)B * NCAND); // B*NCAND u8
    unsigned int* done = (unsigned int*)(labels + (size_t)B * NCAND);     // B u32

    k_zero<<<1, 64, 0, stream>>>(done);
    k_fused<<<B * BLKS_PER_IMG, 1024, 0, stream>>>(x, anchors, scores, labels, done, out);
}

// Round 8
// 93.615 us; speedup vs baseline: 1.9325x; 1.9325x over previous
//
#include <hip/hip_runtime.h>
#include <math.h>

#define B 16
#define A 3
#define W 128
#define HW 16384          // 128*128
#define NCH 255
#define NCLS 80
#define NCAND 49152       // HW*A
#define K 100
#define NBINS 4096
#define CAP 1024

typedef float floatx4 __attribute__((ext_vector_type(4)));

__device__ __forceinline__ float sigmoidf_(float v) {
    return 1.0f / (1.0f + expf(-v));
}

__device__ __forceinline__ bool pair_before(float sa, int ia, float sb, int ib) {
    // "a comes before b" in descending-score, ascending-index order
    return (sa > sb) || (sa == sb && ia < ib);
}

__device__ __forceinline__ floatx4 nt_load4(const float* p) {
    return __builtin_nontemporal_load((const floatx4*)p);
}

// ---- Kernel 1: pure-streaming masked score + class argmax -----------------
// grid: B*A*HW/4/256 = 768 blocks; each thread owns 4 consecutive hw cells
__global__ __launch_bounds__(256) void k_scores(const float* __restrict__ x,
                                                float* __restrict__ scores,
                                                unsigned char* __restrict__ labels) {
    int t = blockIdx.x * 256 + threadIdx.x;
    int b = t / (A * HW / 4);
    int r = t - b * (A * HW / 4);
    int a = r / (HW / 4);
    int q = r - a * (HW / 4);
    int hw = q * 4;
    const float* base = x + (size_t)(b * NCH + a * 85) * HW + hw;

    floatx4 o4 = nt_load4(base + 4 * HW);
    floatx4 m4 = nt_load4(base + 5 * HW);
    int amx = 0, amy = 0, amz = 0, amw = 0;
    #pragma unroll
    for (int c = 1; c < NCLS; ++c) {
        floatx4 v = nt_load4(base + (size_t)(5 + c) * HW);
        bool gx = v.x > m4.x; amx = gx ? c : amx; m4.x = gx ? v.x : m4.x;
        bool gy = v.y > m4.y; amy = gy ? c : amy; m4.y = gy ? v.y : m4.y;
        bool gz = v.z > m4.z; amz = gz ? c : amz; m4.z = gz ? v.z : m4.z;
        bool gw = v.w > m4.w; amw = gw ? c : amw; m4.w = gw ? v.w : m4.w;
    }
    float ol[4] = {o4.x, o4.y, o4.z, o4.w};
    float ml[4] = {m4.x, m4.y, m4.z, m4.w};
    float outv[4];
    #pragma unroll
    for (int l = 0; l < 4; ++l) {
        float obj = sigmoidf_(ol[l]);
        float cls = sigmoidf_(ml[l]);      // sigmoid monotone: max(sig)=sig(max)
        float sc = obj * cls;
        bool valid = (obj >= 0.5f) && (sc >= 0.05f);
        outv[l] = valid ? sc : -1.0f;
    }
    // storage layout [b][a][hw] for coalesced I/O
    size_t off = (size_t)b * NCAND + a * HW + hw;
    *(float4*)(scores + off) = make_float4(outv[0], outv[1], outv[2], outv[3]);
    *(uchar4*)(labels + off) = make_uchar4((unsigned char)amx, (unsigned char)amy,
                                           (unsigned char)amz, (unsigned char)amw);
}

// ---- Kernel 2: per-image hist+select+compact+rank-topk+decode+NMS+write ---
__global__ __launch_bounds__(1024) void k_tail(const float* __restrict__ x,
                                               const float* __restrict__ anchors,
                                               const float* __restrict__ scores,
                                               const unsigned char* __restrict__ labels,
                                               float* __restrict__ out) {
    __shared__ unsigned int lh[NBINS];        // 16 KB
    __shared__ int sh_thr;
    __shared__ unsigned int sh_cnt;
    __shared__ float cs[CAP];
    __shared__ int ci[CAP];
    __shared__ float ts[K];
    __shared__ int tix[K];
    __shared__ float bx[K][4];
    __shared__ float area[K];
    __shared__ int lab[K];
    __shared__ unsigned int sup[K][4];
    __shared__ unsigned int keepw[4];

    int b = blockIdx.x;
    int tid = threadIdx.x;
    const float* sb = scores + (size_t)b * NCAND;

    for (int i = tid; i < NBINS; i += 1024) lh[i] = 0;
    if (tid == 0) { sh_thr = 0; sh_cnt = 0; }
    if (tid < 4) keepw[tid] = 0u;
    for (int i = tid; i < K * 4; i += 1024) ((unsigned int*)sup)[i] = 0u;
    if (tid < K) { ts[tid] = -3.0f; tix[tid] = 0x7FFFFFFF; }
    __syncthreads();

    // pass 1: histogram of valid scores (L2/L3-resident read)
    #pragma unroll
    for (int it = 0; it < 12; ++it) {
        int o = (it * 1024 + tid) * 4;
        float4 v = *(const float4*)(sb + o);
        float sv[4] = {v.x, v.y, v.z, v.w};
        #pragma unroll
        for (int l = 0; l < 4; ++l) {
            float s = sv[l];
            if (s > 0.0f) {
                int bin = (int)(s * (float)NBINS);
                bin = bin > NBINS - 1 ? NBINS - 1 : bin;
                atomicAdd(&lh[bin], 1u);
            }
        }
    }
    __syncthreads();

    // single-wave suffix scan: wave 0 only, no barriers inside
    if (tid < 64) {
        unsigned int c = 0;
        #pragma unroll
        for (int j = 0; j < 64; ++j)
            c += lh[tid * 64 + ((j + tid) & 63)];   // rotated: bank-conflict-free
        unsigned int s = c;
        #pragma unroll
        for (int off = 1; off < 64; off <<= 1) {
            unsigned int v = __shfl_down(s, off);
            if (tid + off < 64) s += v;
        }
        unsigned long long mask = __ballot(s >= K);
        int lstar = -1;
        if (mask) lstar = 63 - __clzll(mask);
        unsigned int snext = 0;
        if (lstar >= 0 && lstar < 63) snext = (unsigned int)__shfl((int)s, lstar + 1);
        if (lstar >= 0 && tid == lstar) {
            unsigned int running = snext;
            int result = lstar * 64;
            for (int bin = lstar * 64 + 63; bin >= lstar * 64; --bin) {
                running += lh[bin];
                if (running >= K) { result = bin; break; }
            }
            sh_thr = result;
        }
        // lstar < 0 (fewer than K valid): sh_thr stays 0 -> take all valid
    }
    __syncthreads();

    // pass 2: compact survivors (bin >= thr) into LDS
    int thr = sh_thr;
    #pragma unroll
    for (int it = 0; it < 12; ++it) {
        int o = (it * 1024 + tid) * 4;
        float4 v = *(const float4*)(sb + o);
        float sv[4] = {v.x, v.y, v.z, v.w};
        #pragma unroll
        for (int l = 0; l < 4; ++l) {
            float s = sv[l];
            if (s > 0.0f && (int)(s * (float)NBINS) >= thr) {
                unsigned int p = atomicAdd(&sh_cnt, 1u);
                if (p < CAP) {
                    int so = o + l;                 // storage offset a*HW+hw
                    int aa = so >> 14;
                    int hh = so & (HW - 1);
                    cs[p] = s;
                    ci[p] = hh * A + aa;            // reference flat index
                }
            }
        }
    }
    __syncthreads();
    int n = (int)sh_cnt; if (n > CAP) n = CAP;

    // one-pass rank select: rank = #pairs strictly before me
    if (tid < n) {
        float s0 = cs[tid]; int i0 = ci[tid];
        int rank = 0;
        for (int j = 0; j < n; ++j)
            rank += pair_before(cs[j], ci[j], s0, i0) ? 1 : 0;
        if (rank < K) { ts[rank] = s0; tix[rank] = i0; }
    }
    __syncthreads();

    // decode boxes + label for valid top-K
    if (tid < K && ts[tid] > 0.0f) {
        int nidx = tix[tid];
        int a = nidx % A;
        int hw = nidx / A;
        int cx = hw % W;
        int cy = hw / W;
        const float* base = x + (size_t)(b * NCH + a * 85) * HW + hw;
        float tx = base[0];
        float ty = base[HW];
        float tw = base[2 * HW];
        float th = base[3 * HW];
        float bcx = (sigmoidf_(tx) + (float)cx) / 128.0f;
        float bcy = (sigmoidf_(ty) + (float)cy) / 128.0f;
        float bw = fminf(fmaxf(expf(tw) * anchors[a * 2 + 0], 0.0f), 2.0f);
        float bh = fminf(fmaxf(expf(th) * anchors[a * 2 + 1], 0.0f), 2.0f);
        float x1 = bcx - 0.5f * bw;
        float y1 = bcy - 0.5f * bh;
        float x2 = x1 + bw;
        float y2 = y1 + bh;
        x1 = fminf(fmaxf(x1, 0.0f), 1.0f);
        y1 = fminf(fmaxf(y1, 0.0f), 1.0f);
        x2 = fminf(fmaxf(x2, 0.0f), 1.0f);
        y2 = fminf(fmaxf(y2, 0.0f), 1.0f);
        bx[tid][0] = x1; bx[tid][1] = y1; bx[tid][2] = x2; bx[tid][3] = y2;
        area[tid] = fmaxf(x2 - x1, 0.0f) * fmaxf(y2 - y1, 0.0f);
        lab[tid] = (int)labels[(size_t)b * NCAND + a * HW + hw];
        atomicOr(&keepw[tid >> 5], 1u << (tid & 31));
    }
    __syncthreads();

    // IoU suppression bitmasks (j > i, both valid)
    for (int p = tid; p < K * K; p += 1024) {
        int i = p / K, j = p % K;
        if (j > i && ts[i] > 0.0f && ts[j] > 0.0f) {
            float lx = fmaxf(bx[i][0], bx[j][0]);
            float ly = fmaxf(bx[i][1], bx[j][1]);
            float rx = fminf(bx[i][2], bx[j][2]);
            float ry = fminf(bx[i][3], bx[j][3]);
            float iw = fmaxf(rx - lx, 0.0f);
            float ih = fmaxf(ry - ly, 0.0f);
            float inter = iw * ih;
            float uni = area[i] + area[j] - inter;
            float iou = inter / fmaxf(uni, 1e-12f);
            if (iou > 0.7f) atomicOr(&sup[i][j >> 5], 1u << (j & 31));
        }
    }
    __syncthreads();

    // greedy scan (register bit-ops, one thread)
    if (tid == 0) {
        unsigned int kw0 = keepw[0], kw1 = keepw[1], kw2 = keepw[2], kw3 = keepw[3];
        for (int i = 0; i < K; ++i) {
            unsigned int kwi = (i < 32) ? kw0 : (i < 64) ? kw1 : (i < 96) ? kw2 : kw3;
            if ((kwi >> (i & 31)) & 1u) {
                kw0 &= ~sup[i][0];
                kw1 &= ~sup[i][1];
                kw2 &= ~sup[i][2];
                kw3 &= ~sup[i][3];
            }
        }
        keepw[0] = kw0; keepw[1] = kw1; keepw[2] = kw2; keepw[3] = kw3;
    }
    __syncthreads();

    // write outputs: boxes | scores | labels | keep (all float32, flat)
    if (tid < K) {
        int kp = (keepw[tid >> 5] >> (tid & 31)) & 1u;
        float sc = ts[tid];
        float* ob = out + (size_t)b * K * 4;
        float* osc = out + (size_t)B * K * 4;
        float* olab = osc + (size_t)B * K;
        float* okp = olab + (size_t)B * K;
        ob[tid * 4 + 0] = kp ? bx[tid][0] : 0.0f;
        ob[tid * 4 + 1] = kp ? bx[tid][1] : 0.0f;
        ob[tid * 4 + 2] = kp ? bx[tid][2] : 0.0f;
        ob[tid * 4 + 3] = kp ? bx[tid][3] : 0.0f;
        osc[b * K + tid] = kp ? sc : 0.0f;
        olab[b * K + tid] = kp ? (float)lab[tid] : -1.0f;
        okp[b * K + tid] = kp ? 1.0f : 0.0f;
    }
}

extern "C" void kernel_launch(void* const* d_in, const int* in_sizes, int n_in,
                              void* d_out, int out_size, void* d_ws, size_t ws_size,
                              hipStream_t stream) {
    const float* x = (const float*)d_in[0];
    const float* anchors = (const float*)d_in[1];
    float* out = (float*)d_out;

    float* scores = (float*)d_ws;                                       // B*NCAND f32 (3 MB)
    unsigned char* labels = (unsigned char*)(scores + (size_t)B * NCAND); // B*NCAND u8

    k_scores<<<(B * A * HW / 4) / 256, 256, 0, stream>>>(x, scores, labels);
    k_tail<<<B, 1024, 0, stream>>>(x, anchors, scores, labels, out);
}

// Round 9
// 70.512 us; speedup vs baseline: 2.5657x; 1.3276x over previous
//
#include <hip/hip_runtime.h>
#include <math.h>

#define B 16
#define A 3
#define W 128
#define HW 16384          // 128*128
#define NCH 255
#define NCLS 80
#define NCAND 49152       // HW*A
#define K 100
#define NBINS 4096
#define CAP 1024

__device__ __forceinline__ float sigmoidf_(float v) {
    return 1.0f / (1.0f + expf(-v));
}

__device__ __forceinline__ bool pair_before(float sa, int ia, float sb, int ib) {
    // "a comes before b" in descending-score, ascending-index order
    return (sa > sb) || (sa == sb && ia < ib);
}

// ---- Kernel 1: pure-streaming masked score + class argmax -----------------
// grid: B*A*HW/4/256 = 768 blocks; each thread owns 4 consecutive hw cells
__global__ __launch_bounds__(256) void k_scores(const float* __restrict__ x,
                                                float* __restrict__ scores,
                                                unsigned char* __restrict__ labels) {
    int t = blockIdx.x * 256 + threadIdx.x;
    int b = t / (A * HW / 4);
    int r = t - b * (A * HW / 4);
    int a = r / (HW / 4);
    int q = r - a * (HW / 4);
    int hw = q * 4;
    const float* base = x + (size_t)(b * NCH + a * 85) * HW + hw;

    float4 o4 = *(const float4*)(base + 4 * HW);
    float4 m4 = *(const float4*)(base + 5 * HW);
    int amx = 0, amy = 0, amz = 0, amw = 0;
    #pragma unroll
    for (int c = 1; c < NCLS; ++c) {
        float4 v = *(const float4*)(base + (size_t)(5 + c) * HW);
        bool gx = v.x > m4.x; amx = gx ? c : amx; m4.x = gx ? v.x : m4.x;
        bool gy = v.y > m4.y; amy = gy ? c : amy; m4.y = gy ? v.y : m4.y;
        bool gz = v.z > m4.z; amz = gz ? c : amz; m4.z = gz ? v.z : m4.z;
        bool gw = v.w > m4.w; amw = gw ? c : amw; m4.w = gw ? v.w : m4.w;
    }
    float ol[4] = {o4.x, o4.y, o4.z, o4.w};
    float ml[4] = {m4.x, m4.y, m4.z, m4.w};
    float outv[4];
    #pragma unroll
    for (int l = 0; l < 4; ++l) {
        float obj = sigmoidf_(ol[l]);
        float cls = sigmoidf_(ml[l]);      // sigmoid monotone: max(sig)=sig(max)
        float sc = obj * cls;
        bool valid = (obj >= 0.5f) && (sc >= 0.05f);
        outv[l] = valid ? sc : -1.0f;
    }
    // storage layout [b][a][hw] for coalesced I/O
    size_t off = (size_t)b * NCAND + a * HW + hw;
    *(float4*)(scores + off) = make_float4(outv[0], outv[1], outv[2], outv[3]);
    *(uchar4*)(labels + off) = make_uchar4((unsigned char)amx, (unsigned char)amy,
                                           (unsigned char)amz, (unsigned char)amw);
}

// ---- Kernel 2: per-image hist+select+compact+rank-topk+decode+NMS+write ---
__global__ __launch_bounds__(1024) void k_tail(const float* __restrict__ x,
                                               const float* __restrict__ anchors,
                                               const float* __restrict__ scores,
                                               const unsigned char* __restrict__ labels,
                                               float* __restrict__ out) {
    __shared__ unsigned int lh[NBINS];        // 16 KB
    __shared__ unsigned int suf[1024];        // 4 KB
    __shared__ int tstar, sh_thr;
    __shared__ unsigned int sh_cnt;
    __shared__ float cs[CAP];
    __shared__ int ci[CAP];
    __shared__ float ts[K];
    __shared__ int tix[K];
    __shared__ float bx[K][4];
    __shared__ float area[K];
    __shared__ int lab[K];
    __shared__ unsigned int sup[K][4];
    __shared__ unsigned int keepw[4];

    int b = blockIdx.x;
    int tid = threadIdx.x;
    const float* sb = scores + (size_t)b * NCAND;

    for (int i = tid; i < NBINS; i += 1024) lh[i] = 0;
    if (tid == 0) { tstar = -1; sh_thr = 0; sh_cnt = 0; }
    if (tid < 4) keepw[tid] = 0u;
    for (int i = tid; i < K * 4; i += 1024) ((unsigned int*)sup)[i] = 0u;
    if (tid < K) { ts[tid] = -3.0f; tix[tid] = 0x7FFFFFFF; }
    __syncthreads();

    // pass 1: histogram of valid scores (L2/L3-resident read)
    #pragma unroll
    for (int it = 0; it < 12; ++it) {
        int o = (it * 1024 + tid) * 4;
        float4 v = *(const float4*)(sb + o);
        float sv[4] = {v.x, v.y, v.z, v.w};
        #pragma unroll
        for (int l = 0; l < 4; ++l) {
            float s = sv[l];
            if (s > 0.0f) {
                int bin = (int)(s * (float)NBINS);
                bin = bin > NBINS - 1 ? NBINS - 1 : bin;
                atomicAdd(&lh[bin], 1u);
            }
        }
    }
    __syncthreads();

    // coarse (x4) suffix scan over 1024 entries
    unsigned int acc = lh[tid * 4] + lh[tid * 4 + 1] +
                       lh[tid * 4 + 2] + lh[tid * 4 + 3];
    suf[tid] = acc;
    __syncthreads();
    for (int off = 1; off < 1024; off <<= 1) {
        unsigned int add = (tid + off < 1024) ? suf[tid + off] : 0u;
        __syncthreads();
        suf[tid] += add;
        __syncthreads();
    }
    if (suf[tid] >= K && (tid == 1023 || suf[tid + 1] < K)) tstar = tid;
    __syncthreads();
    if (tid == 0 && tstar >= 0) {
        int t = tstar;
        unsigned int running = (t < 1023) ? suf[t + 1] : 0u;
        int result = t * 4;
        for (int bin = t * 4 + 3; bin >= t * 4; --bin) {
            running += lh[bin];
            if (running >= K) { result = bin; break; }
        }
        sh_thr = result;
    }
    __syncthreads();

    // pass 2: compact survivors (bin >= thr) into LDS
    int thr = sh_thr;
    #pragma unroll
    for (int it = 0; it < 12; ++it) {
        int o = (it * 1024 + tid) * 4;
        float4 v = *(const float4*)(sb + o);
        float sv[4] = {v.x, v.y, v.z, v.w};
        #pragma unroll
        for (int l = 0; l < 4; ++l) {
            float s = sv[l];
            if (s > 0.0f && (int)(s * (float)NBINS) >= thr) {
                unsigned int p = atomicAdd(&sh_cnt, 1u);
                if (p < CAP) {
                    int so = o + l;                 // storage offset a*HW+hw
                    int aa = so >> 14;
                    int hh = so & (HW - 1);
                    cs[p] = s;
                    ci[p] = hh * A + aa;            // reference flat index
                }
            }
        }
    }
    __syncthreads();
    int n = (int)sh_cnt; if (n > CAP) n = CAP;

    // one-pass rank select: rank = #pairs strictly before me
    if (tid < n) {
        float s0 = cs[tid]; int i0 = ci[tid];
        int rank = 0;
        for (int j = 0; j < n; ++j)
            rank += pair_before(cs[j], ci[j], s0, i0) ? 1 : 0;
        if (rank < K) { ts[rank] = s0; tix[rank] = i0; }
    }
    __syncthreads();

    // decode boxes + label for valid top-K
    if (tid < K && ts[tid] > 0.0f) {
        int nidx = tix[tid];
        int a = nidx % A;
        int hw = nidx / A;
        int cx = hw % W;
        int cy = hw / W;
        const float* base = x + (size_t)(b * NCH + a * 85) * HW + hw;
        float tx = base[0];
        float ty = base[HW];
        float tw = base[2 * HW];
        float th = base[3 * HW];
        float bcx = (sigmoidf_(tx) + (float)cx) / 128.0f;
        float bcy = (sigmoidf_(ty) + (float)cy) / 128.0f;
        float bw = fminf(fmaxf(expf(tw) * anchors[a * 2 + 0], 0.0f), 2.0f);
        float bh = fminf(fmaxf(expf(th) * anchors[a * 2 + 1], 0.0f), 2.0f);
        float x1 = bcx - 0.5f * bw;
        float y1 = bcy - 0.5f * bh;
        float x2 = x1 + bw;
        float y2 = y1 + bh;
        x1 = fminf(fmaxf(x1, 0.0f), 1.0f);
        y1 = fminf(fmaxf(y1, 0.0f), 1.0f);
        x2 = fminf(fmaxf(x2, 0.0f), 1.0f);
        y2 = fminf(fmaxf(y2, 0.0f), 1.0f);
        bx[tid][0] = x1; bx[tid][1] = y1; bx[tid][2] = x2; bx[tid][3] = y2;
        area[tid] = fmaxf(x2 - x1, 0.0f) * fmaxf(y2 - y1, 0.0f);
        lab[tid] = (int)labels[(size_t)b * NCAND + a * HW + hw];
        atomicOr(&keepw[tid >> 5], 1u << (tid & 31));
    }
    __syncthreads();

    // IoU suppression bitmasks (j > i, both valid)
    for (int p = tid; p < K * K; p += 1024) {
        int i = p / K, j = p % K;
        if (j > i && ts[i] > 0.0f && ts[j] > 0.0f) {
            float lx = fmaxf(bx[i][0], bx[j][0]);
            float ly = fmaxf(bx[i][1], bx[j][1]);
            float rx = fminf(bx[i][2], bx[j][2]);
            float ry = fminf(bx[i][3], bx[j][3]);
            float iw = fmaxf(rx - lx, 0.0f);
            float ih = fmaxf(ry - ly, 0.0f);
            float inter = iw * ih;
            float uni = area[i] + area[j] - inter;
            float iou = inter / fmaxf(uni, 1e-12f);
            if (iou > 0.7f) atomicOr(&sup[i][j >> 5], 1u << (j & 31));
        }
    }
    __syncthreads();

    // greedy scan (register bit-ops, one thread)
    if (tid == 0) {
        unsigned int kw0 = keepw[0], kw1 = keepw[1], kw2 = keepw[2], kw3 = keepw[3];
        for (int i = 0; i < K; ++i) {
            unsigned int kwi = (i < 32) ? kw0 : (i < 64) ? kw1 : (i < 96) ? kw2 : kw3;
            if ((kwi >> (i & 31)) & 1u) {
                kw0 &= ~sup[i][0];
                kw1 &= ~sup[i][1];
                kw2 &= ~sup[i][2];
                kw3 &= ~sup[i][3];
            }
        }
        keepw[0] = kw0; keepw[1] = kw1; keepw[2] = kw2; keepw[3] = kw3;
    }
    __syncthreads();

    // write outputs: boxes | scores | labels | keep (all float32, flat)
    if (tid < K) {
        int kp = (keepw[tid >> 5] >> (tid & 31)) & 1u;
        float sc = ts[tid];
        float* ob = out + (size_t)b * K * 4;
        float* osc = out + (size_t)B * K * 4;
        float* olab = osc + (size_t)B * K;
        float* okp = olab + (size_t)B * K;
        ob[tid * 4 + 0] = kp ? bx[tid][0] : 0.0f;
        ob[tid * 4 + 1] = kp ? bx[tid][1] : 0.0f;
        ob[tid * 4 + 2] = kp ? bx[tid][2] : 0.0f;
        ob[tid * 4 + 3] = kp ? bx[tid][3] : 0.0f;
        osc[b * K + tid] = kp ? sc : 0.0f;
        olab[b * K + tid] = kp ? (float)lab[tid] : -1.0f;
        okp[b * K + tid] = kp ? 1.0f : 0.0f;
    }
}

extern "C" void kernel_launch(void* const* d_in, const int* in_sizes, int n_in,
                              void* d_out, int out_size, void* d_ws, size_t ws_size,
                              hipStream_t stream) {
    const float* x = (const float*)d_in[0];
    const float* anchors = (const float*)d_in[1];
    float* out = (float*)d_out;

    float* scores = (float*)d_ws;                                       // B*NCAND f32 (3 MB)
    unsigned char* labels = (unsigned char*)(scores + (size_t)B * NCAND); // B*NCAND u8

    k_scores<<<(B * A * HW / 4) / 256, 256, 0, stream>>>(x, scores, labels);
    k_tail<<<B, 1024, 0, stream>>>(x, anchors, scores, labels, out);
}